// Round 1
// baseline (602.869 us; speedup 1.0000x reference)
//
#include <hip/hip_runtime.h>
#include <hip/hip_bf16.h>
#include <stdint.h>

// Problem constants
#define T_SEQ 2048
#define C_EMB 1024
#define NH    16
#define HD    64
#define BB    4

typedef __attribute__((ext_vector_type(8))) short short8;
typedef __attribute__((ext_vector_type(4))) short short4v;
typedef __attribute__((ext_vector_type(4))) float f32x4;

__device__ __forceinline__ f32x4 mfma16(short8 a, short8 b, f32x4 c) {
  return __builtin_amdgcn_mfma_f32_16x16x32_bf16(a, b, c, 0, 0, 0);
}

// async global->LDS, 16B per lane. LDS dest must be uniform + lane*16.
__device__ __forceinline__ void load_lds16(const void* g, void* l) {
  __builtin_amdgcn_global_load_lds(
      (__attribute__((address_space(1))) void*)(g),
      (__attribute__((address_space(3))) void*)(l), 16, 0, 0);
}

// fp32 -> bf16 RNE
__device__ __forceinline__ unsigned short f2bf(float f) {
  union { float f; unsigned u; } x; x.f = f;
  unsigned r = x.u + 0x7fffu + ((x.u >> 16) & 1u);
  return (unsigned short)(r >> 16);
}

// ---------------- conversion kernels ----------------
__global__ void cvt4(const float* __restrict__ src, unsigned short* __restrict__ dst, int n) {
  int i = (blockIdx.x * 256 + threadIdx.x) * 4;
  if (i < n) {
    float4 v = *reinterpret_cast<const float4*>(src + i);
    short4v o;
    o[0] = (short)f2bf(v.x); o[1] = (short)f2bf(v.y);
    o[2] = (short)f2bf(v.z); o[3] = (short)f2bf(v.w);
    *reinterpret_cast<short4v*>(dst + i) = o;
  }
}

__global__ void pack_bias(const float* __restrict__ bq, const float* __restrict__ bk,
                          const float* __restrict__ bv, float* __restrict__ out) {
  int i = blockIdx.x * 256 + threadIdx.x;
  float v = (i < 1024) ? bq[i] : (i < 2048 ? bk[i - 1024] : bv[i - 2048]);
  out[i] = v;
}

// ---------------- GEMM: C[m][n] = sum_k A[m][k]*Bw[n][k] + bias[n] ----------------
// 128x128 tile, BK=64, 4 waves (2x2), each wave 64x64 via 4x4 of 16x16x32 MFMA.
template <bool OUT_BF16>
__global__ void gemm_bt(const unsigned short* __restrict__ A,
                        const unsigned short* __restrict__ Bw,
                        const float* __restrict__ bias,
                        unsigned short* __restrict__ Cb, float* __restrict__ Cf,
                        int M, int N, int K) {
  __shared__ unsigned short lA[128 * 64];
  __shared__ unsigned short lB[128 * 64];
  const int tid = threadIdx.x;
  const int lane = tid & 63;
  const int w = tid >> 6;
  const int m0 = blockIdx.x * 128;
  const int n0 = blockIdx.y * 128;
  const int wm = (w >> 1) * 64, wn = (w & 1) * 64;

  f32x4 acc[4][4] = {};

  for (int k0 = 0; k0 < K; k0 += 64) {
#pragma unroll
    for (int i = 0; i < 4; ++i) {
      int o = (i * 256 + tid) * 16;           // byte offset within 16KB tile
      int row = o >> 7, colb = o & 127;       // 128 B per row
      load_lds16(A + (size_t)(m0 + row) * K + k0 + (colb >> 1), (char*)lA + o);
      load_lds16(Bw + (size_t)(n0 + row) * K + k0 + (colb >> 1), (char*)lB + o);
    }
    __syncthreads();
#pragma unroll
    for (int kk = 0; kk < 2; ++kk) {
      short8 af[4], bf[4];
#pragma unroll
      for (int mi = 0; mi < 4; ++mi)
        af[mi] = *(const short8*)&lA[(wm + mi * 16 + (lane & 15)) * 64 + kk * 32 + (lane >> 4) * 8];
#pragma unroll
      for (int ni = 0; ni < 4; ++ni)
        bf[ni] = *(const short8*)&lB[(wn + ni * 16 + (lane & 15)) * 64 + kk * 32 + (lane >> 4) * 8];
#pragma unroll
      for (int mi = 0; mi < 4; ++mi)
#pragma unroll
        for (int ni = 0; ni < 4; ++ni)
          acc[mi][ni] = mfma16(af[mi], bf[ni], acc[mi][ni]);
    }
    __syncthreads();
  }
  // epilogue: C/D layout col=lane&15, row=(lane>>4)*4+r
#pragma unroll
  for (int mi = 0; mi < 4; ++mi) {
#pragma unroll
    for (int ni = 0; ni < 4; ++ni) {
#pragma unroll
      for (int r = 0; r < 4; ++r) {
        int m = m0 + wm + mi * 16 + (lane >> 4) * 4 + r;
        int n = n0 + wn + ni * 16 + (lane & 15);
        float v = acc[mi][ni][r] + bias[n];
        if (OUT_BF16) Cb[(size_t)m * N + n] = f2bf(v);
        else          Cf[(size_t)m * N + n] = v;
      }
    }
  }
}

// ---------------- V transpose: qkv V-part [b,t,(h,d)] -> vt[(b,h,d)][t] ----------------
__global__ void vtrans(const unsigned short* __restrict__ qkv, unsigned short* __restrict__ vt) {
  const int tt = blockIdx.x, h = blockIdx.y, b = blockIdx.z;
  const int tid = threadIdx.x;
  __shared__ unsigned short ltile[64][65];
#pragma unroll
  for (int i = 0; i < 2; ++i) {
    int e = i * 2048 + tid * 8;
    int t = e >> 6, d = e & 63;
    short8 v = *(const short8*)(qkv + ((size_t)(b * T_SEQ + tt * 64 + t)) * 3072 + 2048 + h * 64 + d);
#pragma unroll
    for (int j = 0; j < 8; ++j) ltile[d + j][t] = (unsigned short)v[j];
  }
  __syncthreads();
#pragma unroll
  for (int i = 0; i < 2; ++i) {
    int e = i * 2048 + tid * 8;
    int d = e >> 6, t = e & 63;
    short8 sv;
#pragma unroll
    for (int j = 0; j < 8; ++j) sv[j] = (short)ltile[d][t + j];
    *(short8*)(vt + ((size_t)((b * NH + h) * HD + d)) * T_SEQ + tt * 64 + t) = sv;
  }
}

// ---------------- flash attention fwd: y (bf16, [b,t,(h,d)]) + stats (m, 1/l) ----------------
__global__ void flash_fwd(const unsigned short* __restrict__ qkv,
                          const unsigned short* __restrict__ vt,
                          unsigned short* __restrict__ yb,
                          float* __restrict__ mstat, float* __restrict__ lstat) {
  const int qt = blockIdx.x, h = blockIdx.y, b = blockIdx.z;
  const int tid = threadIdx.x, lane = tid & 63, w = tid >> 6;
  __shared__ unsigned short kl[64 * 64];
  __shared__ unsigned short vl[64 * 64];
  __shared__ unsigned short pl[4][16 * 64];
  const int qbase = qt * 64;
  const float scale = 0.125f;

  // Q fragments held in registers for the whole K loop
  short8 qf[2];
  {
    int qr = qbase + w * 16 + (lane & 15);
    const unsigned short* qp = qkv + ((size_t)(b * T_SEQ + qr)) * 3072 + h * 64 + (lane >> 4) * 8;
    qf[0] = *(const short8*)(qp);
    qf[1] = *(const short8*)(qp + 32);
  }

  f32x4 yacc[4] = {};
  float mrow[4], lrow[4];
#pragma unroll
  for (int r = 0; r < 4; ++r) { mrow[r] = -1e30f; lrow[r] = 0.f; }

  for (int kt = 0; kt < T_SEQ / 64; ++kt) {
    int kb = kt * 64;
#pragma unroll
    for (int i = 0; i < 2; ++i) {
      int o = (i * 256 + tid) * 16;
      int row = o >> 7, colb = o & 127;
      load_lds16(qkv + ((size_t)(b * T_SEQ + kb + row)) * 3072 + 1024 + h * 64 + (colb >> 1), (char*)kl + o);
      load_lds16(vt + ((size_t)((b * NH + h) * HD + row)) * T_SEQ + kb + (colb >> 1), (char*)vl + o);
    }
    __syncthreads();

    // S = Q K^T  (raw, scaled later)
    f32x4 s[4] = {};
#pragma unroll
    for (int kk = 0; kk < 2; ++kk) {
#pragma unroll
      for (int ct = 0; ct < 4; ++ct) {
        short8 bfr = *(const short8*)&kl[(ct * 16 + (lane & 15)) * 64 + kk * 32 + (lane >> 4) * 8];
        s[ct] = mfma16(qf[kk], bfr, s[ct]);
      }
    }

    // online softmax per q-row (rows live in lane-groups of 16)
    float alpha[4];
#pragma unroll
    for (int r = 0; r < 4; ++r) {
      float mx = fmaxf(fmaxf(s[0][r], s[1][r]), fmaxf(s[2][r], s[3][r]));
#pragma unroll
      for (int d = 1; d < 16; d <<= 1) mx = fmaxf(mx, __shfl_xor(mx, d));
      float mt = mx * scale;
      float mnew = fmaxf(mrow[r], mt);
      alpha[r] = __expf(mrow[r] - mnew);
      mrow[r] = mnew;
      float sum = 0.f;
#pragma unroll
      for (int ct = 0; ct < 4; ++ct) {
        float p = __expf(s[ct][r] * scale - mnew);
        sum += p;
        pl[w][((lane >> 4) * 4 + r) * 64 + ct * 16 + (lane & 15)] = f2bf(p);
      }
#pragma unroll
      for (int d = 1; d < 16; d <<= 1) sum += __shfl_xor(sum, d);
      lrow[r] = lrow[r] * alpha[r] + sum;
    }
#pragma unroll
    for (int dt = 0; dt < 4; ++dt)
#pragma unroll
      for (int r = 0; r < 4; ++r) yacc[dt][r] *= alpha[r];

    __syncthreads();  // P visible in LDS

    // y += P V
#pragma unroll
    for (int kk = 0; kk < 2; ++kk) {
      short8 pa = *(const short8*)&pl[w][(lane & 15) * 64 + kk * 32 + (lane >> 4) * 8];
#pragma unroll
      for (int dt = 0; dt < 4; ++dt) {
        short8 bv = *(const short8*)&vl[(dt * 16 + (lane & 15)) * 64 + kk * 32 + (lane >> 4) * 8];
        yacc[dt] = mfma16(pa, bv, yacc[dt]);
      }
    }
    __syncthreads();  // all reads done before next stage
  }

#pragma unroll
  for (int r = 0; r < 4; ++r) {
    int qr = qbase + w * 16 + (lane >> 4) * 4 + r;
    float inv = 1.f / lrow[r];
#pragma unroll
    for (int dt = 0; dt < 4; ++dt) {
      float v = yacc[dt][r] * inv;
      yb[((size_t)(b * T_SEQ + qr)) * C_EMB + h * HD + dt * 16 + (lane & 15)] = f2bf(v);
    }
    if ((lane & 15) == 0) {
      mstat[(size_t)(b * NH + h) * T_SEQ + qr] = mrow[r];
      lstat[(size_t)(b * NH + h) * T_SEQ + qr] = inv;
    }
  }
}

// ---------------- att_mean: recompute S per head, accumulate exp(s-m)/l / H ----------------
__global__ void att_mean_k(const unsigned short* __restrict__ qkv,
                           const float* __restrict__ mstat, const float* __restrict__ lstat,
                           float* __restrict__ am) {
  const int ktb = blockIdx.x, qt = blockIdx.y, b = blockIdx.z;
  const int tid = threadIdx.x, lane = tid & 63, w = tid >> 6;
  __shared__ unsigned short kl[64 * 64];
  __shared__ float sm[16][64], sl[16][64];
  const float scale = 0.125f;

  for (int i = tid; i < 16 * 64; i += 256) {
    int h = i >> 6, q = i & 63;
    sm[h][q] = mstat[(size_t)(b * NH + h) * T_SEQ + qt * 64 + q];
    sl[h][q] = lstat[(size_t)(b * NH + h) * T_SEQ + qt * 64 + q];
  }

  f32x4 acc[4] = {};
  for (int h = 0; h < NH; ++h) {
#pragma unroll
    for (int i = 0; i < 2; ++i) {
      int o = (i * 256 + tid) * 16;
      int row = o >> 7, colb = o & 127;
      load_lds16(qkv + ((size_t)(b * T_SEQ + ktb * 64 + row)) * 3072 + 1024 + h * 64 + (colb >> 1), (char*)kl + o);
    }
    short8 qf0, qf1;
    {
      int qr = qt * 64 + w * 16 + (lane & 15);
      const unsigned short* qp = qkv + ((size_t)(b * T_SEQ + qr)) * 3072 + h * 64 + (lane >> 4) * 8;
      qf0 = *(const short8*)qp;
      qf1 = *(const short8*)(qp + 32);
    }
    __syncthreads();  // kl ready (and sm/sl on first iteration)

    f32x4 s[4] = {};
#pragma unroll
    for (int ct = 0; ct < 4; ++ct) {
      short8 b0 = *(const short8*)&kl[(ct * 16 + (lane & 15)) * 64 + (lane >> 4) * 8];
      s[ct] = mfma16(qf0, b0, s[ct]);
      short8 b1 = *(const short8*)&kl[(ct * 16 + (lane & 15)) * 64 + 32 + (lane >> 4) * 8];
      s[ct] = mfma16(qf1, b1, s[ct]);
    }
#pragma unroll
    for (int r = 0; r < 4; ++r) {
      int q = w * 16 + (lane >> 4) * 4 + r;
      float mh = sm[h][q], ilh = sl[h][q];
#pragma unroll
      for (int ct = 0; ct < 4; ++ct)
        acc[ct][r] += __expf(s[ct][r] * scale - mh) * ilh;
    }
    __syncthreads();  // done with kl before next head restage
  }

#pragma unroll
  for (int r = 0; r < 4; ++r) {
    int q = qt * 64 + w * 16 + (lane >> 4) * 4 + r;
#pragma unroll
    for (int ct = 0; ct < 4; ++ct)
      am[((size_t)(b * T_SEQ) + q) * T_SEQ + ktb * 64 + ct * 16 + (lane & 15)] = acc[ct][r] * (1.f / 16.f);
  }
}

// ---------------- launch ----------------
extern "C" void kernel_launch(void* const* d_in, const int* in_sizes, int n_in,
                              void* d_out, int out_size, void* d_ws, size_t ws_size,
                              hipStream_t stream) {
  const float* x  = (const float*)d_in[0];
  const float* Wq = (const float*)d_in[1];
  const float* bq = (const float*)d_in[2];
  const float* Wk = (const float*)d_in[3];
  const float* bk = (const float*)d_in[4];
  const float* Wv = (const float*)d_in[5];
  const float* bv = (const float*)d_in[6];
  const float* Wp = (const float*)d_in[7];
  const float* bp = (const float*)d_in[8];

  char* ws = (char*)d_ws;
  size_t off = 0;
  auto alloc = [&](size_t bytes) { void* p = ws + off; off += (bytes + 255) & ~(size_t)255; return p; };
  unsigned short* xb   = (unsigned short*)alloc((size_t)8192 * 1024 * 2);   // x bf16
  unsigned short* wqkv = (unsigned short*)alloc((size_t)3 * 1024 * 1024 * 2);
  unsigned short* wpb  = (unsigned short*)alloc((size_t)1024 * 1024 * 2);
  unsigned short* qkvb = (unsigned short*)alloc((size_t)8192 * 3072 * 2);   // [b*t][q|k|v]
  unsigned short* vtb  = (unsigned short*)alloc((size_t)BB * NH * HD * T_SEQ * 2);
  unsigned short* ybf  = (unsigned short*)alloc((size_t)8192 * 1024 * 2);
  float* bqkv = (float*)alloc(3072 * 4);
  float* mst  = (float*)alloc((size_t)BB * NH * T_SEQ * 4);
  float* lst  = (float*)alloc((size_t)BB * NH * T_SEQ * 4);

  float* y_out  = (float*)d_out;
  float* am_out = y_out + (size_t)8192 * 1024;

  cvt4<<<8192, 256, 0, stream>>>(x, xb, 8388608);
  cvt4<<<1024, 256, 0, stream>>>(Wq, wqkv, 1048576);
  cvt4<<<1024, 256, 0, stream>>>(Wk, wqkv + 1048576, 1048576);
  cvt4<<<1024, 256, 0, stream>>>(Wv, wqkv + 2097152, 1048576);
  cvt4<<<1024, 256, 0, stream>>>(Wp, wpb, 1048576);
  pack_bias<<<12, 256, 0, stream>>>(bq, bk, bv, bqkv);

  gemm_bt<true><<<dim3(64, 24), 256, 0, stream>>>(xb, wqkv, bqkv, qkvb, nullptr, 8192, 3072, 1024);
  vtrans<<<dim3(32, 16, 4), 256, 0, stream>>>(qkvb, vtb);
  flash_fwd<<<dim3(32, 16, 4), 256, 0, stream>>>(qkvb, vtb, ybf, mst, lst);
  att_mean_k<<<dim3(32, 32, 4), 256, 0, stream>>>(qkvb, mst, lst, am_out);
  gemm_bt<false><<<dim3(64, 8), 256, 0, stream>>>(ybf, wpb, bp, nullptr, y_out, 8192, 1024, 1024);
}

// Round 4
// 551.718 us; speedup vs baseline: 1.0927x; 1.0927x over previous
//
#include <hip/hip_runtime.h>
#include <hip/hip_bf16.h>
#include <stdint.h>

// Problem constants
#define T_SEQ 2048
#define C_EMB 1024
#define NH    16
#define HD    64
#define BB    4

typedef __attribute__((ext_vector_type(8))) short short8;
typedef __attribute__((ext_vector_type(4))) short short4v;
typedef __attribute__((ext_vector_type(4))) float f32x4;

__device__ __forceinline__ f32x4 mfma16(short8 a, short8 b, f32x4 c) {
  return __builtin_amdgcn_mfma_f32_16x16x32_bf16(a, b, c, 0, 0, 0);
}

// async global->LDS, 16B per lane. LDS dest must be uniform + lane*16.
__device__ __forceinline__ void load_lds16(const void* g, void* l) {
  __builtin_amdgcn_global_load_lds(
      (__attribute__((address_space(1))) void*)(g),
      (__attribute__((address_space(3))) void*)(l), 16, 0, 0);
}

// fp32 -> bf16 RNE
__device__ __forceinline__ unsigned short f2bf(float f) {
  union { float f; unsigned u; } x; x.f = f;
  unsigned r = x.u + 0x7fffu + ((x.u >> 16) & 1u);
  return (unsigned short)(r >> 16);
}

// Swizzled fragment read from a [rows][64 bf16] tile (128B rows):
// element (r, c) lives at byte r*128 + ((2c) ^ ((r&7)<<4)).
// 16 consecutive rows at fixed col map to 8 distinct 16B granules (2-way = free).
__device__ __forceinline__ short8 swz_read(const unsigned short* base, int r, int cb) {
  return *(const short8*)((const char*)base + r * 128 + (cb ^ ((r & 7) << 4)));
}

// ---------------- conversion kernels ----------------
__global__ void cvt4(const float* __restrict__ src, unsigned short* __restrict__ dst, int n) {
  int i = (blockIdx.x * 256 + threadIdx.x) * 4;
  if (i < n) {
    float4 v = *reinterpret_cast<const float4*>(src + i);
    short4v o;
    o[0] = (short)f2bf(v.x); o[1] = (short)f2bf(v.y);
    o[2] = (short)f2bf(v.z); o[3] = (short)f2bf(v.w);
    *reinterpret_cast<short4v*>(dst + i) = o;
  }
}

__global__ void pack_bias(const float* __restrict__ bq, const float* __restrict__ bk,
                          const float* __restrict__ bv, float* __restrict__ out) {
  int i = blockIdx.x * 256 + threadIdx.x;
  float v = (i < 1024) ? bq[i] : (i < 2048 ? bk[i - 1024] : bv[i - 2048]);
  out[i] = v;
}

// ---------------- GEMM: C[m][n] = sum_k A[m][k]*Bw[n][k] + bias[n] ----------------
// 128x128 tile, BK=64, 4 waves (2x2), each wave 64x64 via 4x4 of 16x16x32 MFMA.
// m97 structure (validated ~900 TF regime); swizzle is measured-null here at 2-phase.
template <bool OUT_BF16>
__global__ void gemm_bt(const unsigned short* __restrict__ A,
                        const unsigned short* __restrict__ Bw,
                        const float* __restrict__ bias,
                        unsigned short* __restrict__ Cb, float* __restrict__ Cf,
                        int M, int N, int K) {
  __shared__ unsigned short lA[128 * 64];
  __shared__ unsigned short lB[128 * 64];
  const int tid = threadIdx.x;
  const int lane = tid & 63;
  const int w = tid >> 6;
  const int m0 = blockIdx.x * 128;
  const int n0 = blockIdx.y * 128;
  const int wm = (w >> 1) * 64, wn = (w & 1) * 64;

  f32x4 acc[4][4] = {};

  for (int k0 = 0; k0 < K; k0 += 64) {
#pragma unroll
    for (int i = 0; i < 4; ++i) {
      int o = (i * 256 + tid) * 16;           // byte offset within 16KB tile
      int row = o >> 7, colb = o & 127;       // 128 B per row
      load_lds16(A + (size_t)(m0 + row) * K + k0 + (colb >> 1), (char*)lA + o);
      load_lds16(Bw + (size_t)(n0 + row) * K + k0 + (colb >> 1), (char*)lB + o);
    }
    __syncthreads();
#pragma unroll
    for (int kk = 0; kk < 2; ++kk) {
      short8 af[4], bf[4];
#pragma unroll
      for (int mi = 0; mi < 4; ++mi)
        af[mi] = *(const short8*)&lA[(wm + mi * 16 + (lane & 15)) * 64 + kk * 32 + (lane >> 4) * 8];
#pragma unroll
      for (int ni = 0; ni < 4; ++ni)
        bf[ni] = *(const short8*)&lB[(wn + ni * 16 + (lane & 15)) * 64 + kk * 32 + (lane >> 4) * 8];
#pragma unroll
      for (int mi = 0; mi < 4; ++mi)
#pragma unroll
        for (int ni = 0; ni < 4; ++ni)
          acc[mi][ni] = mfma16(af[mi], bf[ni], acc[mi][ni]);
    }
    __syncthreads();
  }
  // epilogue: C/D layout col=lane&15, row=(lane>>4)*4+r
#pragma unroll
  for (int mi = 0; mi < 4; ++mi) {
#pragma unroll
    for (int ni = 0; ni < 4; ++ni) {
#pragma unroll
      for (int r = 0; r < 4; ++r) {
        int m = m0 + wm + mi * 16 + (lane >> 4) * 4 + r;
        int n = n0 + wn + ni * 16 + (lane & 15);
        float v = acc[mi][ni][r] + bias[n];
        if (OUT_BF16) Cb[(size_t)m * N + n] = f2bf(v);
        else          Cf[(size_t)m * N + n] = v;
      }
    }
  }
}

// ---------------- V transpose: qkv V-part [b,t,(h,d)] -> vt[(b,h,d)][t] ----------------
__global__ void vtrans(const unsigned short* __restrict__ qkv, unsigned short* __restrict__ vt) {
  const int tt = blockIdx.x, h = blockIdx.y, b = blockIdx.z;
  const int tid = threadIdx.x;
  __shared__ unsigned short ltile[64][65];
#pragma unroll
  for (int i = 0; i < 2; ++i) {
    int e = i * 2048 + tid * 8;
    int t = e >> 6, d = e & 63;
    short8 v = *(const short8*)(qkv + ((size_t)(b * T_SEQ + tt * 64 + t)) * 3072 + 2048 + h * 64 + d);
#pragma unroll
    for (int j = 0; j < 8; ++j) ltile[d + j][t] = (unsigned short)v[j];
  }
  __syncthreads();
#pragma unroll
  for (int i = 0; i < 2; ++i) {
    int e = i * 2048 + tid * 8;
    int d = e >> 6, t = e & 63;
    short8 sv;
#pragma unroll
    for (int j = 0; j < 8; ++j) sv[j] = (short)ltile[d][t + j];
    *(short8*)(vt + ((size_t)((b * NH + h) * HD + d)) * T_SEQ + tt * 64 + t) = sv;
  }
}

// ---------------- flash attention fwd: y (bf16, [b,t,(h,d)]) + stats (m, 1/l) ----------------
// Double-buffered K/V (prefetch t+1 over compute t), XOR-swizzled LDS
// (kl/vl/pl all 128B-row tiles -> were 16-way bank conflicts), single barrier/tile.
// P (pl) is produced and consumed by the same wave -> no block barrier needed.
__global__ void flash_fwd(const unsigned short* __restrict__ qkv,
                          const unsigned short* __restrict__ vt,
                          unsigned short* __restrict__ yb,
                          float* __restrict__ mstat, float* __restrict__ lstat) {
  const int qt = blockIdx.x, h = blockIdx.y, b = blockIdx.z;
  const int tid = threadIdx.x, lane = tid & 63, w = tid >> 6;
  __shared__ unsigned short kl[2][64 * 64];
  __shared__ unsigned short vl[2][64 * 64];
  __shared__ unsigned short pl[4][16 * 64];
  const int qbase = qt * 64;
  const float scale = 0.125f;

  // Q fragments held in registers for the whole K loop
  short8 qf[2];
  {
    int qr = qbase + w * 16 + (lane & 15);
    const unsigned short* qp = qkv + ((size_t)(b * T_SEQ + qr)) * 3072 + h * 64 + (lane >> 4) * 8;
    qf[0] = *(const short8*)(qp);
    qf[1] = *(const short8*)(qp + 32);
  }

  f32x4 yacc[4] = {};
  float mrow[4], lrow[4];
#pragma unroll
  for (int r = 0; r < 4; ++r) { mrow[r] = -1e30f; lrow[r] = 0.f; }

  // stage tile kb into buffer `buf`, with inverse-swizzled global source so that
  // lds element (row, c) lands at byte row*128 + ((2c) ^ ((row&7)<<4)).
  auto stage = [&](int buf, int kb) {
#pragma unroll
    for (int i = 0; i < 2; ++i) {
      int o = (i * 256 + tid) * 16;
      int row = o >> 7;
      int colb = (o & 127) ^ ((row & 7) << 4);
      load_lds16(qkv + ((size_t)(b * T_SEQ + kb + row)) * 3072 + 1024 + h * 64 + (colb >> 1),
                 (char*)kl[buf] + o);
      load_lds16(vt + ((size_t)((b * NH + h) * HD + row)) * T_SEQ + kb + (colb >> 1),
                 (char*)vl[buf] + o);
    }
  };

  stage(0, 0);
  __syncthreads();   // implicit vmcnt(0) drain: tile 0 resident
  int cur = 0;

  for (int kt = 0; kt < T_SEQ / 64; ++kt) {
    if (kt + 1 < T_SEQ / 64) stage(cur ^ 1, (kt + 1) * 64);  // prefetch overlaps compute

    // S = Q K^T  (raw, scaled later)
    f32x4 s[4] = {};
#pragma unroll
    for (int kk = 0; kk < 2; ++kk) {
#pragma unroll
      for (int ct = 0; ct < 4; ++ct) {
        short8 bfr = swz_read(kl[cur], ct * 16 + (lane & 15), kk * 64 + (lane >> 4) * 16);
        s[ct] = mfma16(qf[kk], bfr, s[ct]);
      }
    }

    // online softmax per q-row (rows live in lane-groups of 16)
    float alpha[4];
#pragma unroll
    for (int r = 0; r < 4; ++r) {
      float mx = fmaxf(fmaxf(s[0][r], s[1][r]), fmaxf(s[2][r], s[3][r]));
#pragma unroll
      for (int d = 1; d < 16; d <<= 1) mx = fmaxf(mx, __shfl_xor(mx, d));
      float mt = mx * scale;
      float mnew = fmaxf(mrow[r], mt);
      alpha[r] = __expf(mrow[r] - mnew);
      mrow[r] = mnew;
      float sum = 0.f;
      int pr = (lane >> 4) * 4 + r;
#pragma unroll
      for (int ct = 0; ct < 4; ++ct) {
        float p = __expf(s[ct][r] * scale - mnew);
        sum += p;
        *(unsigned short*)((char*)pl[w] + pr * 128 +
                           ((ct * 32 + (lane & 15) * 2) ^ ((pr & 7) << 4))) = f2bf(p);
      }
#pragma unroll
      for (int d = 1; d < 16; d <<= 1) sum += __shfl_xor(sum, d);
      lrow[r] = lrow[r] * alpha[r] + sum;
    }
#pragma unroll
    for (int dt = 0; dt < 4; ++dt)
#pragma unroll
      for (int r = 0; r < 4; ++r) yacc[dt][r] *= alpha[r];

    // y += P V   (pl written+read by this wave only: intra-wave lgkmcnt ordering)
#pragma unroll
    for (int kk = 0; kk < 2; ++kk) {
      short8 pa = swz_read(pl[w], lane & 15, kk * 64 + (lane >> 4) * 16);
#pragma unroll
      for (int dt = 0; dt < 4; ++dt) {
        short8 bv = swz_read(vl[cur], dt * 16 + (lane & 15), kk * 64 + (lane >> 4) * 16);
        yacc[dt] = mfma16(pa, bv, yacc[dt]);
      }
    }

    __syncthreads();  // next tile staged + everyone done with cur
    cur ^= 1;
  }

#pragma unroll
  for (int r = 0; r < 4; ++r) {
    int qr = qbase + w * 16 + (lane >> 4) * 4 + r;
    float inv = 1.f / lrow[r];
#pragma unroll
    for (int dt = 0; dt < 4; ++dt) {
      float v = yacc[dt][r] * inv;
      yb[((size_t)(b * T_SEQ + qr)) * C_EMB + h * HD + dt * 16 + (lane & 15)] = f2bf(v);
    }
    if ((lane & 15) == 0) {
      mstat[(size_t)(b * NH + h) * T_SEQ + qr] = mrow[r];
      lstat[(size_t)(b * NH + h) * T_SEQ + qr] = inv;
    }
  }
}

// ---------------- att_mean: recompute S per head, accumulate exp(s-m)/l / H ----------------
// Double-buffered K staging across heads + XOR swizzle.
__global__ void att_mean_k(const unsigned short* __restrict__ qkv,
                           const float* __restrict__ mstat, const float* __restrict__ lstat,
                           float* __restrict__ am) {
  const int ktb = blockIdx.x, qt = blockIdx.y, b = blockIdx.z;
  const int tid = threadIdx.x, lane = tid & 63, w = tid >> 6;
  __shared__ unsigned short kl[2][64 * 64];
  __shared__ float sm[16][64], sl[16][64];
  const float scale = 0.125f;

  auto stage = [&](int buf, int h) {
#pragma unroll
    for (int i = 0; i < 2; ++i) {
      int o = (i * 256 + tid) * 16;
      int row = o >> 7;
      int colb = (o & 127) ^ ((row & 7) << 4);
      load_lds16(qkv + ((size_t)(b * T_SEQ + ktb * 64 + row)) * 3072 + 1024 + h * 64 + (colb >> 1),
                 (char*)kl[buf] + o);
    }
  };

  for (int i = tid; i < 16 * 64; i += 256) {
    int h = i >> 6, q = i & 63;
    sm[h][q] = mstat[(size_t)(b * NH + h) * T_SEQ + qt * 64 + q];
    sl[h][q] = lstat[(size_t)(b * NH + h) * T_SEQ + qt * 64 + q];
  }

  stage(0, 0);
  __syncthreads();
  int cur = 0;

  f32x4 acc[4] = {};
  for (int h = 0; h < NH; ++h) {
    if (h + 1 < NH) stage(cur ^ 1, h + 1);

    short8 qf0, qf1;
    {
      int qr = qt * 64 + w * 16 + (lane & 15);
      const unsigned short* qp = qkv + ((size_t)(b * T_SEQ + qr)) * 3072 + h * 64 + (lane >> 4) * 8;
      qf0 = *(const short8*)qp;
      qf1 = *(const short8*)(qp + 32);
    }

    f32x4 s[4] = {};
#pragma unroll
    for (int ct = 0; ct < 4; ++ct) {
      short8 b0 = swz_read(kl[cur], ct * 16 + (lane & 15), (lane >> 4) * 16);
      s[ct] = mfma16(qf0, b0, s[ct]);
      short8 b1 = swz_read(kl[cur], ct * 16 + (lane & 15), 64 + (lane >> 4) * 16);
      s[ct] = mfma16(qf1, b1, s[ct]);
    }
#pragma unroll
    for (int r = 0; r < 4; ++r) {
      int q = w * 16 + (lane >> 4) * 4 + r;
      float mh = sm[h][q], ilh = sl[h][q];
#pragma unroll
      for (int ct = 0; ct < 4; ++ct)
        acc[ct][r] += __expf(s[ct][r] * scale - mh) * ilh;
    }
    __syncthreads();  // next head staged; everyone done with cur
    cur ^= 1;
  }

#pragma unroll
  for (int r = 0; r < 4; ++r) {
    int q = qt * 64 + w * 16 + (lane >> 4) * 4 + r;
#pragma unroll
    for (int ct = 0; ct < 4; ++ct)
      am[((size_t)(b * T_SEQ) + q) * T_SEQ + ktb * 64 + ct * 16 + (lane & 15)] = acc[ct][r] * (1.f / 16.f);
  }
}

// ---------------- launch ----------------
extern "C" void kernel_launch(void* const* d_in, const int* in_sizes, int n_in,
                              void* d_out, int out_size, void* d_ws, size_t ws_size,
                              hipStream_t stream) {
  const float* x  = (const float*)d_in[0];
  const float* Wq = (const float*)d_in[1];
  const float* bq = (const float*)d_in[2];
  const float* Wk = (const float*)d_in[3];
  const float* bk = (const float*)d_in[4];
  const float* Wv = (const float*)d_in[5];
  const float* bv = (const float*)d_in[6];
  const float* Wp = (const float*)d_in[7];
  const float* bp = (const float*)d_in[8];

  char* ws = (char*)d_ws;
  size_t off = 0;
  auto alloc = [&](size_t bytes) { void* p = ws + off; off += (bytes + 255) & ~(size_t)255; return p; };
  unsigned short* xb   = (unsigned short*)alloc((size_t)8192 * 1024 * 2);   // x bf16
  unsigned short* wqkv = (unsigned short*)alloc((size_t)3 * 1024 * 1024 * 2);
  unsigned short* wpb  = (unsigned short*)alloc((size_t)1024 * 1024 * 2);
  unsigned short* qkvb = (unsigned short*)alloc((size_t)8192 * 3072 * 2);   // [b*t][q|k|v]
  unsigned short* vtb  = (unsigned short*)alloc((size_t)BB * NH * HD * T_SEQ * 2);
  unsigned short* ybf  = (unsigned short*)alloc((size_t)8192 * 1024 * 2);
  float* bqkv = (float*)alloc(3072 * 4);
  float* mst  = (float*)alloc((size_t)BB * NH * T_SEQ * 4);
  float* lst  = (float*)alloc((size_t)BB * NH * T_SEQ * 4);

  float* y_out  = (float*)d_out;
  float* am_out = y_out + (size_t)8192 * 1024;

  cvt4<<<8192, 256, 0, stream>>>(x, xb, 8388608);
  cvt4<<<1024, 256, 0, stream>>>(Wq, wqkv, 1048576);
  cvt4<<<1024, 256, 0, stream>>>(Wk, wqkv + 1048576, 1048576);
  cvt4<<<1024, 256, 0, stream>>>(Wv, wqkv + 2097152, 1048576);
  cvt4<<<1024, 256, 0, stream>>>(Wp, wpb, 1048576);
  pack_bias<<<12, 256, 0, stream>>>(bq, bk, bv, bqkv);

  gemm_bt<true><<<dim3(64, 24), 256, 0, stream>>>(xb, wqkv, bqkv, qkvb, nullptr, 8192, 3072, 1024);
  vtrans<<<dim3(32, 16, 4), 256, 0, stream>>>(qkvb, vtb);
  flash_fwd<<<dim3(32, 16, 4), 256, 0, stream>>>(qkvb, vtb, ybf, mst, lst);
  att_mean_k<<<dim3(32, 32, 4), 256, 0, stream>>>(qkvb, mst, lst, am_out);
  gemm_bt<false><<<dim3(64, 8), 256, 0, stream>>>(ybf, wpb, bp, nullptr, y_out, 8192, 1024, 1024);
}

// Round 8
// 472.982 us; speedup vs baseline: 1.2746x; 1.1665x over previous
//
#include <hip/hip_runtime.h>
#include <hip/hip_bf16.h>
#include <stdint.h>

// Problem constants
#define T_SEQ 2048
#define C_EMB 1024
#define NH    16
#define HD    64
#define BB    4

typedef __attribute__((ext_vector_type(8))) short short8;
typedef __attribute__((ext_vector_type(4))) short short4v;
typedef __attribute__((ext_vector_type(4))) float f32x4;
typedef __attribute__((ext_vector_type(16))) float f32x16;

__device__ __forceinline__ f32x4 mfma16(short8 a, short8 b, f32x4 c) {
  return __builtin_amdgcn_mfma_f32_16x16x32_bf16(a, b, c, 0, 0, 0);
}
__device__ __forceinline__ f32x16 mfma32(short8 a, short8 b, f32x16 c) {
  return __builtin_amdgcn_mfma_f32_32x32x16_bf16(a, b, c, 0, 0, 0);
}

// async global->LDS, 16B per lane. LDS dest must be uniform + lane*16.
__device__ __forceinline__ void load_lds16(const void* g, void* l) {
  __builtin_amdgcn_global_load_lds(
      (__attribute__((address_space(1))) void*)(g),
      (__attribute__((address_space(3))) void*)(l), 16, 0, 0);
}

// fp32 -> bf16 RNE
__device__ __forceinline__ unsigned short f2bf(float f) {
  union { float f; unsigned u; } x; x.f = f;
  unsigned r = x.u + 0x7fffu + ((x.u >> 16) & 1u);
  return (unsigned short)(r >> 16);
}
// pack two f32 -> one u32 of 2xbf16 (lo in bits 0..15) — pure C, no cvt_pk
__device__ __forceinline__ unsigned pack_bf16(float lo, float hi) {
  return (unsigned)f2bf(lo) | ((unsigned)f2bf(hi) << 16);
}

// cross-half (lane ^ 32) exchange via verified __shfl_xor
__device__ __forceinline__ float half_max(float x) { return fmaxf(x, __shfl_xor(x, 32)); }
__device__ __forceinline__ float half_add(float x) { return x + __shfl_xor(x, 32); }

// Swizzled fragment read from a [rows][64 bf16] tile (128B rows):
// element (r, c) lives at byte r*128 + ((2c) ^ ((r&7)<<4)).
__device__ __forceinline__ short8 swz_read(const unsigned short* base, int r, int cb) {
  return *(const short8*)((const char*)base + r * 128 + (cb ^ ((r & 7) << 4)));
}

// log2(e) * softmax scale (1/sqrt(64) = 0.125)
#define C2LOG 0.1803368801111f
#define THR2  11.5f   // defer-max threshold, ~8 nats in log2 domain

// ---------------- conversion kernels ----------------
__global__ void cvt4(const float* __restrict__ src, unsigned short* __restrict__ dst, int n) {
  int i = (blockIdx.x * 256 + threadIdx.x) * 4;
  if (i < n) {
    float4 v = *reinterpret_cast<const float4*>(src + i);
    short4v o;
    o[0] = (short)f2bf(v.x); o[1] = (short)f2bf(v.y);
    o[2] = (short)f2bf(v.z); o[3] = (short)f2bf(v.w);
    *reinterpret_cast<short4v*>(dst + i) = o;
  }
}

__global__ void pack_bias(const float* __restrict__ bq, const float* __restrict__ bk,
                          const float* __restrict__ bv, float* __restrict__ out) {
  int i = blockIdx.x * 256 + threadIdx.x;
  float v = (i < 1024) ? bq[i] : (i < 2048 ? bk[i - 1024] : bv[i - 2048]);
  out[i] = v;
}

// ---------------- GEMM: C[m][n] = sum_k A[m][k]*Bw[n][k] + bias[n] ----------------
template <bool OUT_BF16>
__global__ void gemm_bt(const unsigned short* __restrict__ A,
                        const unsigned short* __restrict__ Bw,
                        const float* __restrict__ bias,
                        unsigned short* __restrict__ Cb, float* __restrict__ Cf,
                        int M, int N, int K) {
  __shared__ unsigned short lA[128 * 64];
  __shared__ unsigned short lB[128 * 64];
  const int tid = threadIdx.x;
  const int lane = tid & 63;
  const int w = tid >> 6;
  const int m0 = blockIdx.x * 128;
  const int n0 = blockIdx.y * 128;
  const int wm = (w >> 1) * 64, wn = (w & 1) * 64;

  f32x4 acc[4][4] = {};

  for (int k0 = 0; k0 < K; k0 += 64) {
#pragma unroll
    for (int i = 0; i < 4; ++i) {
      int o = (i * 256 + tid) * 16;
      int row = o >> 7, colb = o & 127;
      load_lds16(A + (size_t)(m0 + row) * K + k0 + (colb >> 1), (char*)lA + o);
      load_lds16(Bw + (size_t)(n0 + row) * K + k0 + (colb >> 1), (char*)lB + o);
    }
    __syncthreads();
#pragma unroll
    for (int kk = 0; kk < 2; ++kk) {
      short8 af[4], bf[4];
#pragma unroll
      for (int mi = 0; mi < 4; ++mi)
        af[mi] = *(const short8*)&lA[(wm + mi * 16 + (lane & 15)) * 64 + kk * 32 + (lane >> 4) * 8];
#pragma unroll
      for (int ni = 0; ni < 4; ++ni)
        bf[ni] = *(const short8*)&lB[(wn + ni * 16 + (lane & 15)) * 64 + kk * 32 + (lane >> 4) * 8];
#pragma unroll
      for (int mi = 0; mi < 4; ++mi)
#pragma unroll
        for (int ni = 0; ni < 4; ++ni)
          acc[mi][ni] = mfma16(af[mi], bf[ni], acc[mi][ni]);
    }
    __syncthreads();
  }
#pragma unroll
  for (int mi = 0; mi < 4; ++mi) {
#pragma unroll
    for (int ni = 0; ni < 4; ++ni) {
#pragma unroll
      for (int r = 0; r < 4; ++r) {
        int m = m0 + wm + mi * 16 + (lane >> 4) * 4 + r;
        int n = n0 + wn + ni * 16 + (lane & 15);
        float v = acc[mi][ni][r] + bias[n];
        if (OUT_BF16) Cb[(size_t)m * N + n] = f2bf(v);
        else          Cf[(size_t)m * N + n] = v;
      }
    }
  }
}

// ---------------- V transpose: qkv V-part [b,t,(h,d)] -> vt[(b,h,d)][t] ----------------
__global__ void vtrans(const unsigned short* __restrict__ qkv, unsigned short* __restrict__ vt) {
  const int tt = blockIdx.x, h = blockIdx.y, b = blockIdx.z;
  const int tid = threadIdx.x;
  __shared__ unsigned short ltile[64][65];
#pragma unroll
  for (int i = 0; i < 2; ++i) {
    int e = i * 2048 + tid * 8;
    int t = e >> 6, d = e & 63;
    short8 v = *(const short8*)(qkv + ((size_t)(b * T_SEQ + tt * 64 + t)) * 3072 + 2048 + h * 64 + d);
#pragma unroll
    for (int j = 0; j < 8; ++j) ltile[d + j][t] = (unsigned short)v[j];
  }
  __syncthreads();
#pragma unroll
  for (int i = 0; i < 2; ++i) {
    int e = i * 2048 + tid * 8;
    int d = e >> 6, t = e & 63;
    short8 sv;
#pragma unroll
    for (int j = 0; j < 8; ++j) sv[j] = (short)ltile[d][t + j];
    *(short8*)(vt + ((size_t)((b * NH + h) * HD + d)) * T_SEQ + tt * 64 + t) = sv;
  }
}

// ---------------- flash attention fwd, swapped-QK^T 32x32 in-register softmax ----------------
// P-path built from VERIFIED primitives only (f2bf + __shfl_xor + select) — no permlane /
// cvt_pk asm. Layout facts used: mfma32 C/D col=lane&31, row=(r&3)+8*(r>>2)+4*(lane>>5)
// [guide m74/m101]; A/B slot->k maps are identical per MFMA so any common permutation
// cancels (QK^T: A=K,B=Q; PV: A=P,B=V — each pair uses the same read pattern).
__global__ void flash_fwd(const unsigned short* __restrict__ qkv,
                          const unsigned short* __restrict__ vt,
                          unsigned short* __restrict__ yb,
                          float* __restrict__ mstat, float* __restrict__ lstat) {
  const int qt = blockIdx.x, h = blockIdx.y, b = blockIdx.z;
  const int tid = threadIdx.x, lane = tid & 63, w = tid >> 6;
  const int hi = lane >> 5, lq = lane & 31;
  __shared__ unsigned short kl[2][64 * 64];
  __shared__ unsigned short vl[2][64 * 64];
  const int qwave = qt * 128 + w * 32;

  // Q fragments (B-operand): lane holds Q[qwave+lq][dstep*16 + hi*8 + 0..7]
  short8 qf[4];
  {
    const unsigned short* qp = qkv + ((size_t)(b * T_SEQ + qwave + lq)) * 3072 + h * 64 + hi * 8;
#pragma unroll
    for (int dstep = 0; dstep < 4; ++dstep)
      qf[dstep] = *(const short8*)(qp + dstep * 16);
  }

  f32x16 yacc[2] = {};   // O[q][d]: col=lq=d (+32*dtile), row q = (r&3)+8*(r>>2)+4*hi
  float m2 = -3.0e38f, l = 0.f;

  auto stage = [&](int buf, int kb) {
#pragma unroll
    for (int i = 0; i < 2; ++i) {
      int o = (i * 256 + tid) * 16;
      int row = o >> 7;
      int colb = (o & 127) ^ ((row & 7) << 4);
      load_lds16(qkv + ((size_t)(b * T_SEQ + kb + row)) * 3072 + 1024 + h * 64 + (colb >> 1),
                 (char*)kl[buf] + o);
      load_lds16(vt + ((size_t)((b * NH + h) * HD + row)) * T_SEQ + kb + (colb >> 1),
                 (char*)vl[buf] + o);
    }
  };

  stage(0, 0);
  __syncthreads();
  int cur = 0;

  for (int kt = 0; kt < T_SEQ / 64; ++kt) {
    if (kt + 1 < T_SEQ / 64) stage(cur ^ 1, (kt + 1) * 64);

#pragma unroll
    for (int ksc = 0; ksc < 2; ++ksc) {
      // S' = K * Q^T : D[k][q]; lane: q = lq, k = (r&3)+8*(r>>2)+4*hi within 32-chunk
      f32x16 s = {};
      __builtin_amdgcn_s_setprio(1);
#pragma unroll
      for (int dstep = 0; dstep < 4; ++dstep) {
        short8 kf = swz_read(kl[cur], ksc * 32 + lq, dstep * 32 + hi * 16);
        s = mfma32(kf, qf[dstep], s);
      }
      __builtin_amdgcn_s_setprio(0);

      // row max over this 32-kv chunk (log2-scaled)
      float px = fmaxf(fmaxf(fmaxf(s[0], s[1]), fmaxf(s[2], s[3])),
                       fmaxf(fmaxf(s[4], s[5]), fmaxf(s[6], s[7])));
      float px2 = fmaxf(fmaxf(fmaxf(s[8], s[9]), fmaxf(s[10], s[11])),
                        fmaxf(fmaxf(s[12], s[13]), fmaxf(s[14], s[15])));
      px = half_max(fmaxf(px, px2)) * C2LOG;

      // defer-max online update
      if (!__all(px <= m2 + THR2)) {
        float mnew = fmaxf(m2, px);
        float alpha = exp2f(m2 - mnew);
#pragma unroll
        for (int r = 0; r < 16; ++r) {
          float ar = __shfl(alpha, (r & 3) + 8 * (r >> 2) + 4 * hi);
          yacc[0][r] *= ar;
          yacc[1][r] *= ar;
        }
        l *= alpha;
        m2 = mnew;
      }

      // p = exp2(s*C2 - m2); row-sum
      float p[16];
#pragma unroll
      for (int r = 0; r < 16; ++r) p[r] = exp2f(fmaf(s[r], C2LOG, -m2));
      float rs = (((p[0] + p[1]) + (p[2] + p[3])) + ((p[4] + p[5]) + (p[6] + p[7]))) +
                 (((p[8] + p[9]) + (p[10] + p[11])) + ((p[12] + p[13]) + (p[14] + p[15])));
      l += half_add(rs);

      // ---- P -> PV A-fragments, verified primitives only ----
      // word families: w0[c] = P(k={8c,8c+1}+4hi), w1[c] = P(k={8c+2,8c+3}+4hi)
      unsigned w0[4], w1[4];
#pragma unroll
      for (int c = 0; c < 4; ++c) {
        w0[c] = pack_bf16(p[4 * c], p[4 * c + 1]);
        w1[c] = pack_bf16(p[4 * c + 2], p[4 * c + 3]);
      }
      // A-slice ks needs slot (hi, j) = P[q][16ks + 8hi + j]:
      //  u0 (j=0,1): hi=0 -> own w0[2ks];        hi=1 -> partner's w0[2ks+1]
      //  u1 (j=2,3): hi=0 -> own w1[2ks];        hi=1 -> partner's w1[2ks+1]
      //  u2 (j=4,5): hi=0 -> partner's w0[2ks];  hi=1 -> own w0[2ks+1]
      //  u3 (j=6,7): hi=0 -> partner's w1[2ks];  hi=1 -> own w1[2ks+1]
      short8 pa[2];
#pragma unroll
      for (int ks = 0; ks < 2; ++ks) {
        unsigned x0 = w0[2 * ks], x1 = w0[2 * ks + 1];
        unsigned y0 = w1[2 * ks], y1 = w1[2 * ks + 1];
        unsigned px0 = __shfl_xor(x0, 32), px1 = __shfl_xor(x1, 32);
        unsigned py0 = __shfl_xor(y0, 32), py1 = __shfl_xor(y1, 32);
        union { unsigned u[4]; short8 s8; } fu;
        fu.u[0] = hi ? px1 : x0;
        fu.u[1] = hi ? py1 : y0;
        fu.u[2] = hi ? x1  : px0;
        fu.u[3] = hi ? y1  : py0;
        pa[ks] = fu.s8;
      }

      // O += P * V
      __builtin_amdgcn_s_setprio(1);
#pragma unroll
      for (int dtile = 0; dtile < 2; ++dtile) {
#pragma unroll
        for (int ks = 0; ks < 2; ++ks) {
          short8 vf = swz_read(vl[cur], dtile * 32 + lq, ksc * 64 + ks * 32 + hi * 16);
          yacc[dtile] = mfma32(pa[ks], vf, yacc[dtile]);
        }
      }
      __builtin_amdgcn_s_setprio(0);
    }

    __syncthreads();  // next tile staged + everyone done with cur
    cur ^= 1;
  }

  float inv = 1.f / l;
#pragma unroll
  for (int r = 0; r < 16; ++r) {
    int qrow = (r & 3) + 8 * (r >> 2) + 4 * hi;
    float ir = __shfl(inv, qrow);
    size_t base = ((size_t)(b * T_SEQ + qwave + qrow)) * C_EMB + h * 64 + lq;
    yb[base]      = f2bf(yacc[0][r] * ir);
    yb[base + 32] = f2bf(yacc[1][r] * ir);
  }
  if (lane < 32) {
    mstat[(size_t)(b * NH + h) * T_SEQ + qwave + lq] = m2;
    lstat[(size_t)(b * NH + h) * T_SEQ + qwave + lq] = inv;
  }
}

// ---------------- att_mean: recompute S per head, accumulate exp2(s*C2 - m2)/l / H ----------
__global__ void att_mean_k(const unsigned short* __restrict__ qkv,
                           const float* __restrict__ mstat, const float* __restrict__ lstat,
                           float* __restrict__ am) {
  const int ktb = blockIdx.x, qt = blockIdx.y, b = blockIdx.z;
  const int tid = threadIdx.x, lane = tid & 63, w = tid >> 6;
  __shared__ unsigned short kl[2][64 * 64];
  __shared__ float sm[16][64], sl[16][64];

  auto stage = [&](int buf, int h) {
#pragma unroll
    for (int i = 0; i < 2; ++i) {
      int o = (i * 256 + tid) * 16;
      int row = o >> 7;
      int colb = (o & 127) ^ ((row & 7) << 4);
      load_lds16(qkv + ((size_t)(b * T_SEQ + ktb * 64 + row)) * 3072 + 1024 + h * 64 + (colb >> 1),
                 (char*)kl[buf] + o);
    }
  };

  for (int i = tid; i < 16 * 64; i += 256) {
    int h = i >> 6, q = i & 63;
    sm[h][q] = mstat[(size_t)(b * NH + h) * T_SEQ + qt * 64 + q];
    sl[h][q] = lstat[(size_t)(b * NH + h) * T_SEQ + qt * 64 + q];
  }

  stage(0, 0);
  __syncthreads();
  int cur = 0;

  f32x4 acc[4] = {};
  for (int h = 0; h < NH; ++h) {
    if (h + 1 < NH) stage(cur ^ 1, h + 1);

    short8 qf0, qf1;
    {
      int qr = qt * 64 + w * 16 + (lane & 15);
      const unsigned short* qp = qkv + ((size_t)(b * T_SEQ + qr)) * 3072 + h * 64 + (lane >> 4) * 8;
      qf0 = *(const short8*)qp;
      qf1 = *(const short8*)(qp + 32);
    }

    f32x4 s[4] = {};
#pragma unroll
    for (int ct = 0; ct < 4; ++ct) {
      short8 b0 = swz_read(kl[cur], ct * 16 + (lane & 15), (lane >> 4) * 16);
      s[ct] = mfma16(qf0, b0, s[ct]);
      short8 b1 = swz_read(kl[cur], ct * 16 + (lane & 15), 64 + (lane >> 4) * 16);
      s[ct] = mfma16(qf1, b1, s[ct]);
    }
#pragma unroll
    for (int r = 0; r < 4; ++r) {
      int q = w * 16 + (lane >> 4) * 4 + r;
      float mh = sm[h][q], ilh = sl[h][q];
#pragma unroll
      for (int ct = 0; ct < 4; ++ct)
        acc[ct][r] += exp2f(fmaf(s[ct][r], C2LOG, -mh)) * ilh;
    }
    __syncthreads();
    cur ^= 1;
  }

#pragma unroll
  for (int r = 0; r < 4; ++r) {
    int q = qt * 64 + w * 16 + (lane >> 4) * 4 + r;
#pragma unroll
    for (int ct = 0; ct < 4; ++ct)
      am[((size_t)(b * T_SEQ) + q) * T_SEQ + ktb * 64 + ct * 16 + (lane & 15)] = acc[ct][r] * (1.f / 16.f);
  }
}

// ---------------- launch ----------------
extern "C" void kernel_launch(void* const* d_in, const int* in_sizes, int n_in,
                              void* d_out, int out_size, void* d_ws, size_t ws_size,
                              hipStream_t stream) {
  const float* x  = (const float*)d_in[0];
  const float* Wq = (const float*)d_in[1];
  const float* bq = (const float*)d_in[2];
  const float* Wk = (const float*)d_in[3];
  const float* bk = (const float*)d_in[4];
  const float* Wv = (const float*)d_in[5];
  const float* bv = (const float*)d_in[6];
  const float* Wp = (const float*)d_in[7];
  const float* bp = (const float*)d_in[8];

  char* ws = (char*)d_ws;
  size_t off = 0;
  auto alloc = [&](size_t bytes) { void* p = ws + off; off += (bytes + 255) & ~(size_t)255; return p; };
  unsigned short* xb   = (unsigned short*)alloc((size_t)8192 * 1024 * 2);
  unsigned short* wqkv = (unsigned short*)alloc((size_t)3 * 1024 * 1024 * 2);
  unsigned short* wpb  = (unsigned short*)alloc((size_t)1024 * 1024 * 2);
  unsigned short* qkvb = (unsigned short*)alloc((size_t)8192 * 3072 * 2);
  unsigned short* vtb  = (unsigned short*)alloc((size_t)BB * NH * HD * T_SEQ * 2);
  unsigned short* ybf  = (unsigned short*)alloc((size_t)8192 * 1024 * 2);
  float* bqkv = (float*)alloc(3072 * 4);
  float* mst  = (float*)alloc((size_t)BB * NH * T_SEQ * 4);
  float* lst  = (float*)alloc((size_t)BB * NH * T_SEQ * 4);

  float* y_out  = (float*)d_out;
  float* am_out = y_out + (size_t)8192 * 1024;

  cvt4<<<8192, 256, 0, stream>>>(x, xb, 8388608);
  cvt4<<<1024, 256, 0, stream>>>(Wq, wqkv, 1048576);
  cvt4<<<1024, 256, 0, stream>>>(Wk, wqkv + 1048576, 1048576);
  cvt4<<<1024, 256, 0, stream>>>(Wv, wqkv + 2097152, 1048576);
  cvt4<<<1024, 256, 0, stream>>>(Wp, wpb, 1048576);
  pack_bias<<<12, 256, 0, stream>>>(bq, bk, bv, bqkv);

  gemm_bt<true><<<dim3(64, 24), 256, 0, stream>>>(xb, wqkv, bqkv, qkvb, nullptr, 8192, 3072, 1024);
  vtrans<<<dim3(32, 16, 4), 256, 0, stream>>>(qkvb, vtb);
  flash_fwd<<<dim3(16, 16, 4), 256, 0, stream>>>(qkvb, vtb, ybf, mst, lst);
  att_mean_k<<<dim3(32, 32, 4), 256, 0, stream>>>(qkvb, mst, lst, am_out);
  gemm_bt<false><<<dim3(64, 8), 256, 0, stream>>>(ybf, wpb, bp, nullptr, y_out, 8192, 1024, 1024);
}